// Round 13
// baseline (476.550 us; speedup 1.0000x reference)
//
#include <hip/hip_runtime.h>

#define DECAY_F 0.99f
#define OMD_F   0.01f
#define EPS_F   1e-5f

typedef __attribute__((ext_vector_type(8)))  __bf16 bf16x8;
typedef __attribute__((ext_vector_type(16))) float  f32x16;

// ---------------- ws layout (byte offsets) ----------------
#define WSB_CNTI     0          // 1024 i32 (4096)
#define WSB_LOSS     4096       // 256 f32 (1024)
#define WSB_DWACC    8192       // 262144 f32 (1 MB)
#define WSB_CSUM     1056768    // 1 f32 (unused now)
#define WSB_ENORM    1056832    // 1024 f32
#define WSB_IDX      1060928    // 32768 i32
#define WSB_EHI      1192000    // 262144 ushort (FRAG layout)
#define WSB_ELO      1716288    // 262144 ushort (FRAG layout)
#define WSB_SORT     2240576    // 32768 i32
#define WSB_CURS     2371648    // 1024 i32

// ---------------- out layout (float offsets) ----------------
#define OUT_ZQ    0
#define OUT_LOSS  8388608
#define OUT_IDX   8388609
#define OUT_EMB   8421377
#define OUT_CS    8683521
#define OUT_EMAW  8684545

// ---------- bf16 split helpers (RNE, no NaN inputs) ----------
__device__ __forceinline__ unsigned short f2bf(float x) {
    unsigned u = __builtin_bit_cast(unsigned, x);
    u += 0x7fffu + ((u >> 16) & 1u);
    return (unsigned short)(u >> 16);
}
__device__ __forceinline__ float bf2f(unsigned short h) {
    return __builtin_bit_cast(float, (unsigned)h << 16);
}
__device__ __forceinline__ void split8(const float4 a, const float4 b,
                                       uint4& hi, uint4& lo) {
    float f[8] = {a.x, a.y, a.z, a.w, b.x, b.y, b.z, b.w};
    unsigned short h[8], l[8];
    #pragma unroll
    for (int i = 0; i < 8; ++i) {
        h[i] = f2bf(f[i]);
        l[i] = f2bf(f[i] - bf2f(h[i]));
    }
    hi.x = (unsigned)h[0] | ((unsigned)h[1] << 16);
    hi.y = (unsigned)h[2] | ((unsigned)h[3] << 16);
    hi.z = (unsigned)h[4] | ((unsigned)h[5] << 16);
    hi.w = (unsigned)h[6] | ((unsigned)h[7] << 16);
    lo.x = (unsigned)l[0] | ((unsigned)l[1] << 16);
    lo.y = (unsigned)l[2] | ((unsigned)l[3] << 16);
    lo.z = (unsigned)l[4] | ((unsigned)l[5] << 16);
    lo.w = (unsigned)l[6] | ((unsigned)l[7] << 16);
}

// ============ kernel 0: esplit (FRAG layout) + ||e||^2 + zero ws ============
// B' fragment layout: chunk = (g*8 + kc)*2 + kk (g = code>>5, kc = K-step,
// kk = K-half); within a chunk, lane (lh*32+l31) holds code g*32+l31, dims
// kc*32 + (kk*2+lh)*8 .. +8 as 8 bf16 = 16 B. One chunk = 1 KB, so an
// argmin wave's B-fragment load is ONE fully-coalesced 1 KB global load.
// Also zeroes dwacc/cnt/lossbuf/cursor.
__global__ __launch_bounds__(256)
void esplit_enorm_kernel(const float* __restrict__ emb,
                         unsigned short* __restrict__ e_hi,
                         unsigned short* __restrict__ e_lo,
                         float* __restrict__ enorm,
                         float* __restrict__ dwacc,
                         int* __restrict__ cnt,
                         float* __restrict__ lossbuf,
                         int* __restrict__ cursor) {
    const int tid = threadIdx.x, lane = tid & 63, wv = tid >> 6;
    const int gthread = blockIdx.x * 256 + tid;

    // zero accumulators (replaces hipMemsetAsync)
    *(float4*)(dwacc + (size_t)gthread * 4) = make_float4(0.f, 0.f, 0.f, 0.f);
    if (gthread < 1024) { cnt[gthread] = 0; cursor[gthread] = 0; }
    if (gthread < 256)  lossbuf[gthread] = 0.f;

    // frag-layout split: threads 0..32767, one 8-dim granule each
    if (gthread < 32768) {
        const int F     = gthread;
        const int chunk = F >> 6;            // (g*8+kc)*2+kk
        const int lh6   = (F >> 5) & 1;
        const int l31f  = F & 31;
        const int g     = chunk >> 4;
        const int kc    = (chunk >> 1) & 7;
        const int kk    = chunk & 1;
        const int k     = g * 32 + l31f;
        const int d0    = kc * 32 + (kk * 2 + lh6) * 8;
        const float4 v0 = *(const float4*)(emb + (size_t)k * 256 + d0);
        const float4 v1 = *(const float4*)(emb + (size_t)k * 256 + d0 + 4);
        uint4 h, l;
        split8(v0, v1, h, l);
        *(uint4*)((char*)e_hi + (size_t)F * 16) = h;
        *(uint4*)((char*)e_lo + (size_t)F * 16) = l;
    }

    // ||e||^2: wave per code (4 codes per block), coalesced row read
    const int k = blockIdx.x * 4 + wv;
    const float4 v = *(const float4*)(emb + (size_t)k * 256 + lane * 4);
    float s = v.x * v.x + v.y * v.y + v.z * v.z + v.w * v.w;
    #pragma unroll
    for (int off = 32; off > 0; off >>= 1) s += __shfl_down(s, off);
    if (lane == 0) enorm[k] = s;
}

// ============ kernel 1: barrier-free MFMA mega-argmin (32-row, 3/CU) ============
// R13 retile: R12's addr-lean structure (proven 77 us at 64 rows, 2 blocks/CU)
// was latency-bound with MFMA+VALU both idle ~56% and only 2 waves/SIMD to
// hide stalls. Halve the block: 32 rows x 1024 codes, 1024 blocks, wave tile
// 32x64 (acc[2] = 32 regs), LDS 32 KB -> __launch_bounds__(256,3) targets
// 3 blocks/CU = 3 waves/SIMD (+50% latency hiding). Total MFMA unchanged.
// B L2 traffic doubles (1 MB/block, L2-resident e_hi/e_lo) - acceptable.
// Addresses stay uniform-base + lane*16 + immediates (R12). s-loop NOT
// unrolled (R6 spill lesson). No ticket/fence epilogue (R8 lesson).
__global__ __launch_bounds__(256, 3)
void argmin_kernel(const float* __restrict__ z,
                   const unsigned short* __restrict__ e_hi,
                   const unsigned short* __restrict__ e_lo,
                   const float* __restrict__ enorm,
                   const float* __restrict__ emb,
                   int* __restrict__ idx, float* __restrict__ idxf,
                   float* __restrict__ out_zq, int* __restrict__ cnt) {
    __shared__ unsigned short Ah[16 * 512], Al[16 * 512];   // 16 KB each

    const int tid  = threadIdx.x;
    const int lane = tid & 63;
    const int wv   = tid >> 6;
    const int l31  = lane & 31, lh = lane >> 5;
    const int row0 = blockIdx.x * 32;
    const int vOff = lane * 16;              // per-lane byte offset (1 VGPR)

    // ---- A init: split 32 rows x 256 dims into frag-layout LDS, once ----
    // chunk C = kc*2 + kk (16 chunks x 1 KB); lane l31 = row, lh = k-half.
    #pragma unroll
    for (int c8 = 0; c8 < 4; ++c8) {
        const int C  = wv * 4 + c8;
        const int kc = C >> 1, kk = C & 1;
        const int row = row0 + l31;
        const int d0  = kc * 32 + (kk * 2 + lh) * 8;
        const float4 v0 = *(const float4*)(z + (size_t)row * 256 + d0);
        const float4 v1 = *(const float4*)(z + (size_t)row * 256 + d0 + 4);
        uint4 h, l;
        split8(v0, v1, h, l);
        *(uint4*)((char*)Ah + (size_t)C * 1024 + vOff) = h;
        *(uint4*)((char*)Al + (size_t)C * 1024 + vOff) = l;
    }
    __syncthreads();     // the ONLY barrier before the epilogue

    f32x16 acc[2];
    #pragma unroll
    for (int j = 0; j < 2; ++j) acc[j] = (f32x16)0.0f;

    float bestd[16];
    int   besti[16];
    #pragma unroll
    for (int r = 0; r < 16; ++r) { bestd[r] = 3.4e38f; besti[r] = 0; }

    // B fragment loads: byte = csp*131072 + wv*32768 + j*16384 + kc*2048
    //                        + kk*1024 + lane*16
    // uniform part -> SGPR base; lane*16 -> voffset; j/kk -> immediates.
    const char* ehW = (const char*)e_hi + (size_t)wv * 32768;
    const char* elW = (const char*)e_lo + (size_t)wv * 32768;
    uint4 b0h[4], b0l[4], b1h[4], b1l[4];
    auto loadB = [&](int s, uint4* bh, uint4* bl) {
        const int off = ((s >> 3) << 17) + ((s & 7) << 11);   // uniform (SALU)
        const char* ph = ehW + off;
        const char* pl = elW + off;
        bh[0] = *(const uint4*)(ph + vOff);            // j=0,kk=0
        bh[1] = *(const uint4*)(ph + vOff + 1024);     // j=0,kk=1
        bh[2] = *(const uint4*)(ph + vOff + 16384);    // j=1,kk=0
        bh[3] = *(const uint4*)(ph + vOff + 17408);    // j=1,kk=1
        bl[0] = *(const uint4*)(pl + vOff);
        bl[1] = *(const uint4*)(pl + vOff + 1024);
        bl[2] = *(const uint4*)(pl + vOff + 16384);
        bl[3] = *(const uint4*)(pl + vOff + 17408);
    };
    // A LDS reads: byte = kc*2048 + kk*1024 + lane*16
    auto compute = [&](int s, const uint4* bh4, const uint4* bl4) {
        const int kcoff = (s & 7) << 11;               // uniform (SALU)
        const char* pa = (const char*)Ah + vOff + kcoff;
        const char* pb = (const char*)Al + vOff + kcoff;
        #pragma unroll
        for (int kk = 0; kk < 2; ++kk) {
            bf16x8 bh[2], bl[2];
            #pragma unroll
            for (int j = 0; j < 2; ++j) {
                bh[j] = __builtin_bit_cast(bf16x8, bh4[j * 2 + kk]);
                bl[j] = __builtin_bit_cast(bf16x8, bl4[j * 2 + kk]);
            }
            const bf16x8 ah = __builtin_bit_cast(bf16x8,
                *(const uint4*)(pa + kk * 1024));
            const bf16x8 al = __builtin_bit_cast(bf16x8,
                *(const uint4*)(pb + kk * 1024));
            #pragma unroll
            for (int j = 0; j < 2; ++j) {
                acc[j] = __builtin_amdgcn_mfma_f32_32x32x16_bf16(ah, bh[j], acc[j], 0, 0, 0);
                acc[j] = __builtin_amdgcn_mfma_f32_32x32x16_bf16(al, bh[j], acc[j], 0, 0, 0);
                acc[j] = __builtin_amdgcn_mfma_f32_32x32x16_bf16(ah, bl[j], acc[j], 0, 0, 0);
            }
        }
        if ((s & 7) == 7) {   // end of this 256-code split: fold distances
            const int csp = s >> 3;
            #pragma unroll
            for (int j = 0; j < 2; ++j) {
                const int col = csp * 256 + wv * 64 + j * 32 + l31;
                const float en = enorm[col];
                #pragma unroll
                for (int r = 0; r < 16; ++r) {
                    const float d = fmaf(-2.0f, acc[j][r], en);
                    // strict <: fold candidates ascend in col (R12 proven)
                    if (d < bestd[r]) { bestd[r] = d; besti[r] = col; }
                }
            }
            #pragma unroll
            for (int j = 0; j < 2; ++j) acc[j] = (f32x16)0.0f;
        }
    };

    loadB(0, b0h, b0l);
    for (int s = 0; s < 32; s += 2) {
        loadB(s + 1, b1h, b1l);
        compute(s, b0h, b0l);
        if (s + 2 < 32) loadB(s + 2, b0h, b0l);
        compute(s + 1, b1h, b1l);
    }

    // ---- butterfly over the 32 col lanes (keeps lane>>5 fixed) ----
    #pragma unroll
    for (int m = 1; m < 32; m <<= 1) {
        #pragma unroll
        for (int r = 0; r < 16; ++r) {
            const float od = __shfl_xor(bestd[r], m);
            const int   oi = __shfl_xor(besti[r], m);
            if (od < bestd[r] || (od == bestd[r] && oi < besti[r])) {
                bestd[r] = od; besti[r] = oi;
            }
        }
    }

    // ---- merge the 4 waves via LDS -> FINAL argmin; write idx/counts ----
    __syncthreads();
    float* mg_d = (float*)Ah;                 // [4][32] floats
    int*   mg_i = (int*)Ah + 128;             // [4][32] ints
    if (l31 == 0) {
        #pragma unroll
        for (int r = 0; r < 16; ++r) {
            const int rloc = (r & 3) + 8 * (r >> 2) + 4 * lh;   // 0..31
            mg_d[wv * 32 + rloc] = bestd[r];
            mg_i[wv * 32 + rloc] = besti[r];
        }
    }
    __syncthreads();
    if (tid < 32) {
        float d0 = mg_d[tid];
        int   i0 = mg_i[tid];
        #pragma unroll
        for (int w = 1; w < 4; ++w) {   // wave col-ranges interleave: full comparator
            const float dw = mg_d[w * 32 + tid];
            const int   iw = mg_i[w * 32 + tid];
            if (dw < d0 || (dw == d0 && iw < i0)) { d0 = dw; i0 = iw; }
        }
        const int n = row0 + tid;
        idx[n] = i0; idxf[n] = (float)i0;
        atomicAdd(&cnt[i0], 1);
        mg_i[tid] = i0;                  // publish final codes for the gather
    }
    __syncthreads();

    // ---- gather z_q: each wave writes 8 rows (emb is L2/L3-resident) ----
    #pragma unroll 4
    for (int r = 0; r < 8; ++r) {
        const int row = wv * 8 + r;
        const int code = mg_i[row];
        const float4 e4 = *(const float4*)(emb + (size_t)code * 256 + lane * 4);
        *(float4*)(out_zq + (size_t)(row0 + row) * 256 + lane * 4) = e4;
    }
}

// ============ kernel 2: scatter (self-computed prefix) ============
// Each of the 128 blocks redundantly computes the exclusive prefix of cnt
// (1024 ints, L2-hot) into LDS sbase, then scatters its 256 rows:
// within-code rank via cursor atomics (cursor zeroed by esplit),
// final slot = sbase[k] + rank. No cross-block communication.
__global__ __launch_bounds__(256)
void scatter_kernel(const int* __restrict__ idx, const int* __restrict__ cnt,
                    int* __restrict__ cursor, int* __restrict__ sorted) {
    __shared__ int sbase[1024];
    __shared__ int wsum[4];
    const int t = threadIdx.x, lane = t & 63, wv = t >> 6;

    int c[4]; int ts = 0;
    #pragma unroll
    for (int i = 0; i < 4; ++i) { c[i] = cnt[t * 4 + i]; ts += c[i]; }
    int v = ts;
    #pragma unroll
    for (int o = 1; o < 64; o <<= 1) { const int u = __shfl_up(v, o); if (lane >= o) v += u; }
    if (lane == 63) wsum[wv] = v;
    __syncthreads();
    int wbase = 0;
    #pragma unroll
    for (int w = 0; w < 4; ++w) if (w < wv) wbase += wsum[w];
    int base = wbase + v - ts;                // exclusive prefix, codes ascending
    #pragma unroll
    for (int i = 0; i < 4; ++i) { sbase[t * 4 + i] = base; base += c[i]; }
    __syncthreads();

    const int n = blockIdx.x * 256 + t;
    const int k = idx[n];
    const int r = atomicAdd(&cursor[k], 1);
    sorted[sbase[k] + r] = n;
}

// ============ kernel 3: dw + loss — wave per 16 sorted rows (R5 PROVEN) ============
// 16 rows/wave is the measured optimum (64/16/8 tried; 8 doubled flush
// atomics and lost 15 us). loss per run computed algebraically:
// sum||z-e||^2 = sum(z^2) - 2 e.S + cnt*||e||^2
__global__ __launch_bounds__(256)
void dw_kernel(const float* __restrict__ z, const float* __restrict__ emb,
               const float* __restrict__ enorm,
               const int* __restrict__ sorted, const int* __restrict__ idx,
               float* __restrict__ dwacc, float* __restrict__ lossbuf) {
    const int lane = threadIdx.x & 63;
    const int w    = blockIdx.x * 4 + (threadIdx.x >> 6);
    const int r0   = w * 16;
    const int srow = sorted[r0 + (lane & 15)];
    const int skey = idx[srow];

    float4 s = make_float4(0.f, 0.f, 0.f, 0.f);
    float sumsq = 0.f;
    int cntr = 0;
    int krun = __shfl(skey, 0);

    auto flush = [&](int k) {
        const float4 e = *(const float4*)(emb + (size_t)k * 256 + lane * 4);
        float val = sumsq - 2.0f * (e.x * s.x + e.y * s.y + e.z * s.z + e.w * s.w);
        #pragma unroll
        for (int off = 32; off > 0; off >>= 1) val += __shfl_down(val, off);
        if (lane == 0) atomicAdd(&lossbuf[k & 255], val + (float)cntr * enorm[k]);
        float* p = dwacc + (size_t)k * 256 + lane * 4;
        atomicAdd(p + 0, s.x); atomicAdd(p + 1, s.y);
        atomicAdd(p + 2, s.z); atomicAdd(p + 3, s.w);
    };

    #pragma unroll 8
    for (int j = 0; j < 16; ++j) {
        const int row = __shfl(srow, j);
        const int k   = __shfl(skey, j);
        if (k != krun) {
            flush(krun);
            s = make_float4(0.f, 0.f, 0.f, 0.f);
            sumsq = 0.f; cntr = 0; krun = k;
        }
        const float4 v = *(const float4*)(z + (size_t)row * 256 + lane * 4);
        s.x += v.x; s.y += v.y; s.z += v.z; s.w += v.w;
        sumsq += v.x * v.x + v.y * v.y + v.z * v.z + v.w * v.w;
        ++cntr;
    }
    flush(krun);
}

// ============ kernel 4: EMA-w / embedding epilogue (self-computed n_total) ============
__global__ __launch_bounds__(256)
void update_w_kernel(const float* __restrict__ ema_cs, const int* __restrict__ cnt,
                     const float* __restrict__ ema_w, const float* __restrict__ dwacc,
                     const float* __restrict__ lossbuf,
                     float* __restrict__ out_cs,
                     float* __restrict__ out_emb, float* __restrict__ out_emaw,
                     float* __restrict__ out_loss) {
    __shared__ float red[256];
    const int t = threadIdx.x;

    // redundant n_total reduction (matches scan's f-sum semantics)
    float fv[4]; float fsum = 0.f;
    #pragma unroll
    for (int i = 0; i < 4; ++i) {
        const int k4 = t * 4 + i;
        const float f = DECAY_F * ema_cs[k4] + OMD_F * (float)cnt[k4];
        fv[i] = f; fsum += f;
    }
    red[t] = fsum; __syncthreads();
    #pragma unroll
    for (int off = 128; off > 0; off >>= 1) {
        if (t < off) red[t] += red[t + off];
        __syncthreads();
    }
    const float n_total = red[0];
    __syncthreads();                 // red reused below by block 0

    if (blockIdx.x == 0) {
        #pragma unroll
        for (int i = 0; i < 4; ++i) out_cs[t * 4 + i] = fv[i];
        red[t] = lossbuf[t]; __syncthreads();
        #pragma unroll
        for (int off = 128; off > 0; off >>= 1) {
            if (t < off) red[t] += red[t + off];
            __syncthreads();
        }
        if (t == 0) out_loss[0] = 1.25f * red[0] / 8388608.0f;
    }

    const int g = blockIdx.x * 256 + t;          // float4 slot, 0..65535
    const int k = g >> 6;
    const float fk = DECAY_F * ema_cs[k] + OMD_F * (float)cnt[k];
    const float cs = (fk + EPS_F) / (n_total + 1024.0f * EPS_F) * n_total;

    const float4 w4 = *(const float4*)(ema_w + (size_t)g * 4);
    const float4 d4 = *(const float4*)(dwacc + (size_t)g * 4);
    float4 nw, ne;
    nw.x = DECAY_F * w4.x + OMD_F * d4.x;
    nw.y = DECAY_F * w4.y + OMD_F * d4.y;
    nw.z = DECAY_F * w4.z + OMD_F * d4.z;
    nw.w = DECAY_F * w4.w + OMD_F * d4.w;
    ne.x = nw.x / cs; ne.y = nw.y / cs; ne.z = nw.z / cs; ne.w = nw.w / cs;
    *(float4*)(out_emaw + (size_t)g * 4) = nw;
    *(float4*)(out_emb  + (size_t)g * 4) = ne;
}

// ======================= launcher =======================
extern "C" void kernel_launch(void* const* d_in, const int* in_sizes, int n_in,
                              void* d_out, int out_size, void* d_ws, size_t ws_size,
                              hipStream_t stream) {
    const float* z      = (const float*)d_in[0];
    const float* emb    = (const float*)d_in[1];
    const float* ema_cs = (const float*)d_in[2];
    const float* ema_w  = (const float*)d_in[3];

    float* out = (float*)d_out;
    char*  wsb = (char*)d_ws;

    int*            cnt     = (int*)(wsb + WSB_CNTI);
    float*          lossbuf = (float*)(wsb + WSB_LOSS);
    float*          dwacc   = (float*)(wsb + WSB_DWACC);
    float*          enorm   = (float*)(wsb + WSB_ENORM);
    int*            idx     = (int*)(wsb + WSB_IDX);
    unsigned short* e_hi    = (unsigned short*)(wsb + WSB_EHI);
    unsigned short* e_lo    = (unsigned short*)(wsb + WSB_ELO);
    int*            sorted  = (int*)(wsb + WSB_SORT);
    int*            cursor  = (int*)(wsb + WSB_CURS);

    float* out_zq   = out + OUT_ZQ;
    float* out_loss = out + OUT_LOSS;
    float* out_idxf = out + OUT_IDX;
    float* out_emb  = out + OUT_EMB;
    float* out_cs   = out + OUT_CS;
    float* out_emaw = out + OUT_EMAW;

    esplit_enorm_kernel<<<256, 256, 0, stream>>>(emb, e_hi, e_lo, enorm,
                                                 dwacc, cnt, lossbuf, cursor);
    argmin_kernel<<<1024, 256, 0, stream>>>(z, e_hi, e_lo, enorm, emb,
                                            idx, out_idxf, out_zq, cnt);
    scatter_kernel<<<128, 256, 0, stream>>>(idx, cnt, cursor, sorted);
    dw_kernel<<<512, 256, 0, stream>>>(z, emb, enorm, sorted, idx, dwacc, lossbuf);
    update_w_kernel<<<256, 256, 0, stream>>>(ema_cs, cnt, ema_w, dwacc, lossbuf,
                                             out_cs, out_emb, out_emaw, out_loss);
}

// Round 14
// 260.188 us; speedup vs baseline: 1.8316x; 1.8316x over previous
//
#include <hip/hip_runtime.h>

#define DECAY_F 0.99f
#define OMD_F   0.01f
#define EPS_F   1e-5f

typedef __attribute__((ext_vector_type(8)))  __bf16 bf16x8;
typedef __attribute__((ext_vector_type(16))) float  f32x16;

// ---------------- ws layout (byte offsets) ----------------
#define WSB_CNTI     0          // 1024 i32 (4096)
#define WSB_LOSS     4096       // 256 f32 (1024)
#define WSB_DWACC    8192       // 262144 f32 (1 MB)
#define WSB_CSUM     1056768    // 1 f32 (unused now)
#define WSB_ENORM    1056832    // 1024 f32
#define WSB_IDX      1060928    // 32768 i32
#define WSB_EHI      1192000    // 262144 ushort (FRAG layout)
#define WSB_ELO      1716288    // 262144 ushort (FRAG layout)
#define WSB_SORT     2240576    // 32768 i32
#define WSB_CURS     2371648    // 1024 i32

// ---------------- out layout (float offsets) ----------------
#define OUT_ZQ    0
#define OUT_LOSS  8388608
#define OUT_IDX   8388609
#define OUT_EMB   8421377
#define OUT_CS    8683521
#define OUT_EMAW  8684545

// ---------- bf16 split helpers (RNE, no NaN inputs) ----------
__device__ __forceinline__ unsigned short f2bf(float x) {
    unsigned u = __builtin_bit_cast(unsigned, x);
    u += 0x7fffu + ((u >> 16) & 1u);
    return (unsigned short)(u >> 16);
}
__device__ __forceinline__ float bf2f(unsigned short h) {
    return __builtin_bit_cast(float, (unsigned)h << 16);
}
__device__ __forceinline__ void split8(const float4 a, const float4 b,
                                       uint4& hi, uint4& lo) {
    float f[8] = {a.x, a.y, a.z, a.w, b.x, b.y, b.z, b.w};
    unsigned short h[8], l[8];
    #pragma unroll
    for (int i = 0; i < 8; ++i) {
        h[i] = f2bf(f[i]);
        l[i] = f2bf(f[i] - bf2f(h[i]));
    }
    hi.x = (unsigned)h[0] | ((unsigned)h[1] << 16);
    hi.y = (unsigned)h[2] | ((unsigned)h[3] << 16);
    hi.z = (unsigned)h[4] | ((unsigned)h[5] << 16);
    hi.w = (unsigned)h[6] | ((unsigned)h[7] << 16);
    lo.x = (unsigned)l[0] | ((unsigned)l[1] << 16);
    lo.y = (unsigned)l[2] | ((unsigned)l[3] << 16);
    lo.z = (unsigned)l[4] | ((unsigned)l[5] << 16);
    lo.w = (unsigned)l[6] | ((unsigned)l[7] << 16);
}

// ============ kernel 0: esplit (FRAG layout) + ||e||^2 + zero ws ============
// B' fragment layout: chunk = (g*8 + kc)*2 + kk (g = code>>5, kc = K-step,
// kk = K-half); within a chunk, lane (lh*32+l31) holds code g*32+l31, dims
// kc*32 + (kk*2+lh)*8 .. +8 as 8 bf16 = 16 B. One chunk = 1 KB, so an
// argmin wave's B-fragment load is ONE fully-coalesced 1 KB global load.
// Also zeroes dwacc/cnt/lossbuf/cursor.
__global__ __launch_bounds__(256)
void esplit_enorm_kernel(const float* __restrict__ emb,
                         unsigned short* __restrict__ e_hi,
                         unsigned short* __restrict__ e_lo,
                         float* __restrict__ enorm,
                         float* __restrict__ dwacc,
                         int* __restrict__ cnt,
                         float* __restrict__ lossbuf,
                         int* __restrict__ cursor) {
    const int tid = threadIdx.x, lane = tid & 63, wv = tid >> 6;
    const int gthread = blockIdx.x * 256 + tid;

    // zero accumulators (replaces hipMemsetAsync)
    *(float4*)(dwacc + (size_t)gthread * 4) = make_float4(0.f, 0.f, 0.f, 0.f);
    if (gthread < 1024) { cnt[gthread] = 0; cursor[gthread] = 0; }
    if (gthread < 256)  lossbuf[gthread] = 0.f;

    // frag-layout split: threads 0..32767, one 8-dim granule each
    if (gthread < 32768) {
        const int F     = gthread;
        const int chunk = F >> 6;            // (g*8+kc)*2+kk
        const int lh6   = (F >> 5) & 1;
        const int l31f  = F & 31;
        const int g     = chunk >> 4;
        const int kc    = (chunk >> 1) & 7;
        const int kk    = chunk & 1;
        const int k     = g * 32 + l31f;
        const int d0    = kc * 32 + (kk * 2 + lh6) * 8;
        const float4 v0 = *(const float4*)(emb + (size_t)k * 256 + d0);
        const float4 v1 = *(const float4*)(emb + (size_t)k * 256 + d0 + 4);
        uint4 h, l;
        split8(v0, v1, h, l);
        *(uint4*)((char*)e_hi + (size_t)F * 16) = h;
        *(uint4*)((char*)e_lo + (size_t)F * 16) = l;
    }

    // ||e||^2: wave per code (4 codes per block), coalesced row read
    const int k = blockIdx.x * 4 + wv;
    const float4 v = *(const float4*)(emb + (size_t)k * 256 + lane * 4);
    float s = v.x * v.x + v.y * v.y + v.z * v.z + v.w * v.w;
    #pragma unroll
    for (int off = 32; off > 0; off >>= 1) s += __shfl_down(s, off);
    if (lane == 0) enorm[k] = s;
}

// ============ kernel 1: barrier-free MFMA mega-argmin (32-row) ============
// R14: the R13 32-row retile rerun at the PROVEN register budget.
// R13's __launch_bounds__(256,3) gave an 84-reg budget (hipcc maps arg=N to
// 512/(2N) regs for 256-thread blocks) -> spilled B/acc to scratch (WRITE
// 34->835 MB, 5x time). (256,2) = 128-reg budget, proven non-spilling all
// session; the 32-row kernel needs LESS than R12's 116. Occupancy then
// bounded by LDS (32 KB -> up to 5 blocks/CU) and regs (~4 waves/SIMD):
// expect 3-4 blocks/CU vs R12's 2 = the latency-hiding this retile targets.
// 32 rows x 1024 codes, 1024 blocks, wave tile 32x64 (acc[2] = 32 regs).
// Addresses uniform-base + lane*16 + immediates (R12). s-loop NOT unrolled
// (R6 spill). No ticket/fence epilogue (R8).
__global__ __launch_bounds__(256, 2)
void argmin_kernel(const float* __restrict__ z,
                   const unsigned short* __restrict__ e_hi,
                   const unsigned short* __restrict__ e_lo,
                   const float* __restrict__ enorm,
                   const float* __restrict__ emb,
                   int* __restrict__ idx, float* __restrict__ idxf,
                   float* __restrict__ out_zq, int* __restrict__ cnt) {
    __shared__ unsigned short Ah[16 * 512], Al[16 * 512];   // 16 KB each

    const int tid  = threadIdx.x;
    const int lane = tid & 63;
    const int wv   = tid >> 6;
    const int l31  = lane & 31, lh = lane >> 5;
    const int row0 = blockIdx.x * 32;
    const int vOff = lane * 16;              // per-lane byte offset (1 VGPR)

    // ---- A init: split 32 rows x 256 dims into frag-layout LDS, once ----
    // chunk C = kc*2 + kk (16 chunks x 1 KB); lane l31 = row, lh = k-half.
    #pragma unroll
    for (int c8 = 0; c8 < 4; ++c8) {
        const int C  = wv * 4 + c8;
        const int kc = C >> 1, kk = C & 1;
        const int row = row0 + l31;
        const int d0  = kc * 32 + (kk * 2 + lh) * 8;
        const float4 v0 = *(const float4*)(z + (size_t)row * 256 + d0);
        const float4 v1 = *(const float4*)(z + (size_t)row * 256 + d0 + 4);
        uint4 h, l;
        split8(v0, v1, h, l);
        *(uint4*)((char*)Ah + (size_t)C * 1024 + vOff) = h;
        *(uint4*)((char*)Al + (size_t)C * 1024 + vOff) = l;
    }
    __syncthreads();     // the ONLY barrier before the epilogue

    f32x16 acc[2];
    #pragma unroll
    for (int j = 0; j < 2; ++j) acc[j] = (f32x16)0.0f;

    float bestd[16];
    int   besti[16];
    #pragma unroll
    for (int r = 0; r < 16; ++r) { bestd[r] = 3.4e38f; besti[r] = 0; }

    // B fragment loads: byte = csp*131072 + wv*32768 + j*16384 + kc*2048
    //                        + kk*1024 + lane*16
    // uniform part -> SGPR base; lane*16 -> voffset; j/kk -> immediates.
    const char* ehW = (const char*)e_hi + (size_t)wv * 32768;
    const char* elW = (const char*)e_lo + (size_t)wv * 32768;
    uint4 b0h[4], b0l[4], b1h[4], b1l[4];
    auto loadB = [&](int s, uint4* bh, uint4* bl) {
        const int off = ((s >> 3) << 17) + ((s & 7) << 11);   // uniform (SALU)
        const char* ph = ehW + off;
        const char* pl = elW + off;
        bh[0] = *(const uint4*)(ph + vOff);            // j=0,kk=0
        bh[1] = *(const uint4*)(ph + vOff + 1024);     // j=0,kk=1
        bh[2] = *(const uint4*)(ph + vOff + 16384);    // j=1,kk=0
        bh[3] = *(const uint4*)(ph + vOff + 17408);    // j=1,kk=1
        bl[0] = *(const uint4*)(pl + vOff);
        bl[1] = *(const uint4*)(pl + vOff + 1024);
        bl[2] = *(const uint4*)(pl + vOff + 16384);
        bl[3] = *(const uint4*)(pl + vOff + 17408);
    };
    // A LDS reads: byte = kc*2048 + kk*1024 + lane*16
    auto compute = [&](int s, const uint4* bh4, const uint4* bl4) {
        const int kcoff = (s & 7) << 11;               // uniform (SALU)
        const char* pa = (const char*)Ah + vOff + kcoff;
        const char* pb = (const char*)Al + vOff + kcoff;
        #pragma unroll
        for (int kk = 0; kk < 2; ++kk) {
            bf16x8 bh[2], bl[2];
            #pragma unroll
            for (int j = 0; j < 2; ++j) {
                bh[j] = __builtin_bit_cast(bf16x8, bh4[j * 2 + kk]);
                bl[j] = __builtin_bit_cast(bf16x8, bl4[j * 2 + kk]);
            }
            const bf16x8 ah = __builtin_bit_cast(bf16x8,
                *(const uint4*)(pa + kk * 1024));
            const bf16x8 al = __builtin_bit_cast(bf16x8,
                *(const uint4*)(pb + kk * 1024));
            #pragma unroll
            for (int j = 0; j < 2; ++j) {
                acc[j] = __builtin_amdgcn_mfma_f32_32x32x16_bf16(ah, bh[j], acc[j], 0, 0, 0);
                acc[j] = __builtin_amdgcn_mfma_f32_32x32x16_bf16(al, bh[j], acc[j], 0, 0, 0);
                acc[j] = __builtin_amdgcn_mfma_f32_32x32x16_bf16(ah, bl[j], acc[j], 0, 0, 0);
            }
        }
        if ((s & 7) == 7) {   // end of this 256-code split: fold distances
            const int csp = s >> 3;
            #pragma unroll
            for (int j = 0; j < 2; ++j) {
                const int col = csp * 256 + wv * 64 + j * 32 + l31;
                const float en = enorm[col];
                #pragma unroll
                for (int r = 0; r < 16; ++r) {
                    const float d = fmaf(-2.0f, acc[j][r], en);
                    // strict <: fold candidates ascend in col (R12 proven)
                    if (d < bestd[r]) { bestd[r] = d; besti[r] = col; }
                }
            }
            #pragma unroll
            for (int j = 0; j < 2; ++j) acc[j] = (f32x16)0.0f;
        }
    };

    loadB(0, b0h, b0l);
    for (int s = 0; s < 32; s += 2) {
        loadB(s + 1, b1h, b1l);
        compute(s, b0h, b0l);
        if (s + 2 < 32) loadB(s + 2, b0h, b0l);
        compute(s + 1, b1h, b1l);
    }

    // ---- butterfly over the 32 col lanes (keeps lane>>5 fixed) ----
    #pragma unroll
    for (int m = 1; m < 32; m <<= 1) {
        #pragma unroll
        for (int r = 0; r < 16; ++r) {
            const float od = __shfl_xor(bestd[r], m);
            const int   oi = __shfl_xor(besti[r], m);
            if (od < bestd[r] || (od == bestd[r] && oi < besti[r])) {
                bestd[r] = od; besti[r] = oi;
            }
        }
    }

    // ---- merge the 4 waves via LDS -> FINAL argmin; write idx/counts ----
    __syncthreads();
    float* mg_d = (float*)Ah;                 // [4][32] floats
    int*   mg_i = (int*)Ah + 128;             // [4][32] ints
    if (l31 == 0) {
        #pragma unroll
        for (int r = 0; r < 16; ++r) {
            const int rloc = (r & 3) + 8 * (r >> 2) + 4 * lh;   // 0..31
            mg_d[wv * 32 + rloc] = bestd[r];
            mg_i[wv * 32 + rloc] = besti[r];
        }
    }
    __syncthreads();
    if (tid < 32) {
        float d0 = mg_d[tid];
        int   i0 = mg_i[tid];
        #pragma unroll
        for (int w = 1; w < 4; ++w) {   // wave col-ranges interleave: full comparator
            const float dw = mg_d[w * 32 + tid];
            const int   iw = mg_i[w * 32 + tid];
            if (dw < d0 || (dw == d0 && iw < i0)) { d0 = dw; i0 = iw; }
        }
        const int n = row0 + tid;
        idx[n] = i0; idxf[n] = (float)i0;
        atomicAdd(&cnt[i0], 1);
        mg_i[tid] = i0;                  // publish final codes for the gather
    }
    __syncthreads();

    // ---- gather z_q: each wave writes 8 rows (emb is L2/L3-resident) ----
    #pragma unroll 4
    for (int r = 0; r < 8; ++r) {
        const int row = wv * 8 + r;
        const int code = mg_i[row];
        const float4 e4 = *(const float4*)(emb + (size_t)code * 256 + lane * 4);
        *(float4*)(out_zq + (size_t)(row0 + row) * 256 + lane * 4) = e4;
    }
}

// ============ kernel 2: scatter (self-computed prefix) ============
// Each of the 128 blocks redundantly computes the exclusive prefix of cnt
// (1024 ints, L2-hot) into LDS sbase, then scatters its 256 rows:
// within-code rank via cursor atomics (cursor zeroed by esplit),
// final slot = sbase[k] + rank. No cross-block communication.
__global__ __launch_bounds__(256)
void scatter_kernel(const int* __restrict__ idx, const int* __restrict__ cnt,
                    int* __restrict__ cursor, int* __restrict__ sorted) {
    __shared__ int sbase[1024];
    __shared__ int wsum[4];
    const int t = threadIdx.x, lane = t & 63, wv = t >> 6;

    int c[4]; int ts = 0;
    #pragma unroll
    for (int i = 0; i < 4; ++i) { c[i] = cnt[t * 4 + i]; ts += c[i]; }
    int v = ts;
    #pragma unroll
    for (int o = 1; o < 64; o <<= 1) { const int u = __shfl_up(v, o); if (lane >= o) v += u; }
    if (lane == 63) wsum[wv] = v;
    __syncthreads();
    int wbase = 0;
    #pragma unroll
    for (int w = 0; w < 4; ++w) if (w < wv) wbase += wsum[w];
    int base = wbase + v - ts;                // exclusive prefix, codes ascending
    #pragma unroll
    for (int i = 0; i < 4; ++i) { sbase[t * 4 + i] = base; base += c[i]; }
    __syncthreads();

    const int n = blockIdx.x * 256 + t;
    const int k = idx[n];
    const int r = atomicAdd(&cursor[k], 1);
    sorted[sbase[k] + r] = n;
}

// ============ kernel 3: dw + loss — wave per 16 sorted rows (R5 PROVEN) ============
// 16 rows/wave is the measured optimum (64/16/8 tried; 8 doubled flush
// atomics and lost 15 us). loss per run computed algebraically:
// sum||z-e||^2 = sum(z^2) - 2 e.S + cnt*||e||^2
__global__ __launch_bounds__(256)
void dw_kernel(const float* __restrict__ z, const float* __restrict__ emb,
               const float* __restrict__ enorm,
               const int* __restrict__ sorted, const int* __restrict__ idx,
               float* __restrict__ dwacc, float* __restrict__ lossbuf) {
    const int lane = threadIdx.x & 63;
    const int w    = blockIdx.x * 4 + (threadIdx.x >> 6);
    const int r0   = w * 16;
    const int srow = sorted[r0 + (lane & 15)];
    const int skey = idx[srow];

    float4 s = make_float4(0.f, 0.f, 0.f, 0.f);
    float sumsq = 0.f;
    int cntr = 0;
    int krun = __shfl(skey, 0);

    auto flush = [&](int k) {
        const float4 e = *(const float4*)(emb + (size_t)k * 256 + lane * 4);
        float val = sumsq - 2.0f * (e.x * s.x + e.y * s.y + e.z * s.z + e.w * s.w);
        #pragma unroll
        for (int off = 32; off > 0; off >>= 1) val += __shfl_down(val, off);
        if (lane == 0) atomicAdd(&lossbuf[k & 255], val + (float)cntr * enorm[k]);
        float* p = dwacc + (size_t)k * 256 + lane * 4;
        atomicAdd(p + 0, s.x); atomicAdd(p + 1, s.y);
        atomicAdd(p + 2, s.z); atomicAdd(p + 3, s.w);
    };

    #pragma unroll 8
    for (int j = 0; j < 16; ++j) {
        const int row = __shfl(srow, j);
        const int k   = __shfl(skey, j);
        if (k != krun) {
            flush(krun);
            s = make_float4(0.f, 0.f, 0.f, 0.f);
            sumsq = 0.f; cntr = 0; krun = k;
        }
        const float4 v = *(const float4*)(z + (size_t)row * 256 + lane * 4);
        s.x += v.x; s.y += v.y; s.z += v.z; s.w += v.w;
        sumsq += v.x * v.x + v.y * v.y + v.z * v.z + v.w * v.w;
        ++cntr;
    }
    flush(krun);
}

// ============ kernel 4: EMA-w / embedding epilogue (self-computed n_total) ============
__global__ __launch_bounds__(256)
void update_w_kernel(const float* __restrict__ ema_cs, const int* __restrict__ cnt,
                     const float* __restrict__ ema_w, const float* __restrict__ dwacc,
                     const float* __restrict__ lossbuf,
                     float* __restrict__ out_cs,
                     float* __restrict__ out_emb, float* __restrict__ out_emaw,
                     float* __restrict__ out_loss) {
    __shared__ float red[256];
    const int t = threadIdx.x;

    // redundant n_total reduction (matches scan's f-sum semantics)
    float fv[4]; float fsum = 0.f;
    #pragma unroll
    for (int i = 0; i < 4; ++i) {
        const int k4 = t * 4 + i;
        const float f = DECAY_F * ema_cs[k4] + OMD_F * (float)cnt[k4];
        fv[i] = f; fsum += f;
    }
    red[t] = fsum; __syncthreads();
    #pragma unroll
    for (int off = 128; off > 0; off >>= 1) {
        if (t < off) red[t] += red[t + off];
        __syncthreads();
    }
    const float n_total = red[0];
    __syncthreads();                 // red reused below by block 0

    if (blockIdx.x == 0) {
        #pragma unroll
        for (int i = 0; i < 4; ++i) out_cs[t * 4 + i] = fv[i];
        red[t] = lossbuf[t]; __syncthreads();
        #pragma unroll
        for (int off = 128; off > 0; off >>= 1) {
            if (t < off) red[t] += red[t + off];
            __syncthreads();
        }
        if (t == 0) out_loss[0] = 1.25f * red[0] / 8388608.0f;
    }

    const int g = blockIdx.x * 256 + t;          // float4 slot, 0..65535
    const int k = g >> 6;
    const float fk = DECAY_F * ema_cs[k] + OMD_F * (float)cnt[k];
    const float cs = (fk + EPS_F) / (n_total + 1024.0f * EPS_F) * n_total;

    const float4 w4 = *(const float4*)(ema_w + (size_t)g * 4);
    const float4 d4 = *(const float4*)(dwacc + (size_t)g * 4);
    float4 nw, ne;
    nw.x = DECAY_F * w4.x + OMD_F * d4.x;
    nw.y = DECAY_F * w4.y + OMD_F * d4.y;
    nw.z = DECAY_F * w4.z + OMD_F * d4.z;
    nw.w = DECAY_F * w4.w + OMD_F * d4.w;
    ne.x = nw.x / cs; ne.y = nw.y / cs; ne.z = nw.z / cs; ne.w = nw.w / cs;
    *(float4*)(out_emaw + (size_t)g * 4) = nw;
    *(float4*)(out_emb  + (size_t)g * 4) = ne;
}

// ======================= launcher =======================
extern "C" void kernel_launch(void* const* d_in, const int* in_sizes, int n_in,
                              void* d_out, int out_size, void* d_ws, size_t ws_size,
                              hipStream_t stream) {
    const float* z      = (const float*)d_in[0];
    const float* emb    = (const float*)d_in[1];
    const float* ema_cs = (const float*)d_in[2];
    const float* ema_w  = (const float*)d_in[3];

    float* out = (float*)d_out;
    char*  wsb = (char*)d_ws;

    int*            cnt     = (int*)(wsb + WSB_CNTI);
    float*          lossbuf = (float*)(wsb + WSB_LOSS);
    float*          dwacc   = (float*)(wsb + WSB_DWACC);
    float*          enorm   = (float*)(wsb + WSB_ENORM);
    int*            idx     = (int*)(wsb + WSB_IDX);
    unsigned short* e_hi    = (unsigned short*)(wsb + WSB_EHI);
    unsigned short* e_lo    = (unsigned short*)(wsb + WSB_ELO);
    int*            sorted  = (int*)(wsb + WSB_SORT);
    int*            cursor  = (int*)(wsb + WSB_CURS);

    float* out_zq   = out + OUT_ZQ;
    float* out_loss = out + OUT_LOSS;
    float* out_idxf = out + OUT_IDX;
    float* out_emb  = out + OUT_EMB;
    float* out_cs   = out + OUT_CS;
    float* out_emaw = out + OUT_EMAW;

    esplit_enorm_kernel<<<256, 256, 0, stream>>>(emb, e_hi, e_lo, enorm,
                                                 dwacc, cnt, lossbuf, cursor);
    argmin_kernel<<<1024, 256, 0, stream>>>(z, e_hi, e_lo, enorm, emb,
                                            idx, out_idxf, out_zq, cnt);
    scatter_kernel<<<128, 256, 0, stream>>>(idx, cnt, cursor, sorted);
    dw_kernel<<<512, 256, 0, stream>>>(z, emb, enorm, sorted, idx, dwacc, lossbuf);
    update_w_kernel<<<256, 256, 0, stream>>>(ema_cs, cnt, ema_w, dwacc, lossbuf,
                                             out_cs, out_emb, out_emaw, out_loss);
}

// Round 15
// 200.076 us; speedup vs baseline: 2.3818x; 1.3004x over previous
//
#include <hip/hip_runtime.h>

#define DECAY_F 0.99f
#define OMD_F   0.01f
#define EPS_F   1e-5f

typedef __attribute__((ext_vector_type(8)))  __bf16 bf16x8;
typedef __attribute__((ext_vector_type(16))) float  f32x16;

// ---------------- ws layout (byte offsets) ----------------
#define WSB_CNTI     0          // 1024 i32 (4096)
#define WSB_LOSS     4096       // 256 f32 (1024)
#define WSB_DWACC    8192       // 262144 f32 (1 MB)
#define WSB_CSUM     1056768    // 1 f32 (unused now)
#define WSB_ENORM    1056832    // 1024 f32
#define WSB_IDX      1060928    // 32768 i32
#define WSB_EHI      1192000    // 262144 ushort (FRAG layout)
#define WSB_ELO      1716288    // 262144 ushort (FRAG layout)
#define WSB_SORT     2240576    // 32768 i32
#define WSB_CURS     2371648    // 1024 i32

// ---------------- out layout (float offsets) ----------------
#define OUT_ZQ    0
#define OUT_LOSS  8388608
#define OUT_IDX   8388609
#define OUT_EMB   8421377
#define OUT_CS    8683521
#define OUT_EMAW  8684545

// ---------- bf16 split helpers (RNE, no NaN inputs) ----------
__device__ __forceinline__ unsigned short f2bf(float x) {
    unsigned u = __builtin_bit_cast(unsigned, x);
    u += 0x7fffu + ((u >> 16) & 1u);
    return (unsigned short)(u >> 16);
}
__device__ __forceinline__ float bf2f(unsigned short h) {
    return __builtin_bit_cast(float, (unsigned)h << 16);
}
__device__ __forceinline__ void split8(const float4 a, const float4 b,
                                       uint4& hi, uint4& lo) {
    float f[8] = {a.x, a.y, a.z, a.w, b.x, b.y, b.z, b.w};
    unsigned short h[8], l[8];
    #pragma unroll
    for (int i = 0; i < 8; ++i) {
        h[i] = f2bf(f[i]);
        l[i] = f2bf(f[i] - bf2f(h[i]));
    }
    hi.x = (unsigned)h[0] | ((unsigned)h[1] << 16);
    hi.y = (unsigned)h[2] | ((unsigned)h[3] << 16);
    hi.z = (unsigned)h[4] | ((unsigned)h[5] << 16);
    hi.w = (unsigned)h[6] | ((unsigned)h[7] << 16);
    lo.x = (unsigned)l[0] | ((unsigned)l[1] << 16);
    lo.y = (unsigned)l[2] | ((unsigned)l[3] << 16);
    lo.z = (unsigned)l[4] | ((unsigned)l[5] << 16);
    lo.w = (unsigned)l[6] | ((unsigned)l[7] << 16);
}

// ============ kernel 0: esplit (FRAG layout) + ||e||^2 + zero ws ============
// B' fragment layout: chunk = (g*8 + kc)*2 + kk (g = code>>5, kc = K-step,
// kk = K-half); within a chunk, lane (lh*32+l31) holds code g*32+l31, dims
// kc*32 + (kk*2+lh)*8 .. +8 as 8 bf16 = 16 B. One chunk = 1 KB, so an
// argmin wave's B-fragment load is ONE fully-coalesced 1 KB global load.
// Also zeroes dwacc/cnt/lossbuf/cursor.
__global__ __launch_bounds__(256)
void esplit_enorm_kernel(const float* __restrict__ emb,
                         unsigned short* __restrict__ e_hi,
                         unsigned short* __restrict__ e_lo,
                         float* __restrict__ enorm,
                         float* __restrict__ dwacc,
                         int* __restrict__ cnt,
                         float* __restrict__ lossbuf,
                         int* __restrict__ cursor) {
    const int tid = threadIdx.x, lane = tid & 63, wv = tid >> 6;
    const int gthread = blockIdx.x * 256 + tid;

    // zero accumulators (replaces hipMemsetAsync)
    *(float4*)(dwacc + (size_t)gthread * 4) = make_float4(0.f, 0.f, 0.f, 0.f);
    if (gthread < 1024) { cnt[gthread] = 0; cursor[gthread] = 0; }
    if (gthread < 256)  lossbuf[gthread] = 0.f;

    // frag-layout split: threads 0..32767, one 8-dim granule each
    if (gthread < 32768) {
        const int F     = gthread;
        const int chunk = F >> 6;            // (g*8+kc)*2+kk
        const int lh6   = (F >> 5) & 1;
        const int l31f  = F & 31;
        const int g     = chunk >> 4;
        const int kc    = (chunk >> 1) & 7;
        const int kk    = chunk & 1;
        const int k     = g * 32 + l31f;
        const int d0    = kc * 32 + (kk * 2 + lh6) * 8;
        const float4 v0 = *(const float4*)(emb + (size_t)k * 256 + d0);
        const float4 v1 = *(const float4*)(emb + (size_t)k * 256 + d0 + 4);
        uint4 h, l;
        split8(v0, v1, h, l);
        *(uint4*)((char*)e_hi + (size_t)F * 16) = h;
        *(uint4*)((char*)e_lo + (size_t)F * 16) = l;
    }

    // ||e||^2: wave per code (4 codes per block), coalesced row read
    const int k = blockIdx.x * 4 + wv;
    const float4 v = *(const float4*)(emb + (size_t)k * 256 + lane * 4);
    float s = v.x * v.x + v.y * v.y + v.z * v.z + v.w * v.w;
    #pragma unroll
    for (int off = 32; off > 0; off >>= 1) s += __shfl_down(s, off);
    if (lane == 0) enorm[k] = s;
}

// ============ kernel 1: barrier-free MFMA mega-argmin (64-row, R12 + combo-ILP) ============
// R12 structure (proven 77 us): 512 blocks (2/CU), 64 rows x 1024 codes,
// wave tile 64x64 (acc[2][2]), addr-lean uniform-base + lane*16 + immediates.
// R15's single change: MFMA combos ordered OUTERMOST — all 4 independent
// acc[i][j] are updated per combo before the next combo touches any of them
// (dependency distance 4 vs R12's 3 back-to-back dependent MFMAs on one acc).
// +8 VGPR (ah/al for both i live together), ~124 <= 128 budget.
// R14 refuted the 32-row retile (intensity halves, occupancy doesn't rise).
// s-loop NOT unrolled (R6 spill). No ticket/fence epilogue (R8).
// __launch_bounds__ 2nd arg stays 2 = 128-reg budget (R13: arg=3 -> 84 regs -> spill).
__global__ __launch_bounds__(256, 2)
void argmin_kernel(const float* __restrict__ z,
                   const unsigned short* __restrict__ e_hi,
                   const unsigned short* __restrict__ e_lo,
                   const float* __restrict__ enorm,
                   const float* __restrict__ emb,
                   int* __restrict__ idx, float* __restrict__ idxf,
                   float* __restrict__ out_zq, int* __restrict__ cnt) {
    __shared__ unsigned short Ah[32 * 512], Al[32 * 512];   // 32 KB each

    const int tid  = threadIdx.x;
    const int lane = tid & 63;
    const int wv   = tid >> 6;
    const int l31  = lane & 31, lh = lane >> 5;
    const int row0 = blockIdx.x * 64;
    const int vOff = lane * 16;              // per-lane byte offset (1 VGPR)

    // ---- A init: split 64 rows x 256 dims into frag-layout LDS, once ----
    #pragma unroll
    for (int c8 = 0; c8 < 8; ++c8) {
        const int C  = wv * 8 + c8;
        const int i  = C >> 4, kc = (C >> 1) & 7, kk = C & 1;
        const int row = row0 + i * 32 + l31;
        const int d0  = kc * 32 + (kk * 2 + lh) * 8;
        const float4 v0 = *(const float4*)(z + (size_t)row * 256 + d0);
        const float4 v1 = *(const float4*)(z + (size_t)row * 256 + d0 + 4);
        uint4 h, l;
        split8(v0, v1, h, l);
        *(uint4*)((char*)Ah + (size_t)C * 1024 + vOff) = h;
        *(uint4*)((char*)Al + (size_t)C * 1024 + vOff) = l;
    }
    __syncthreads();     // the ONLY barrier before the epilogue

    f32x16 acc[2][2];
    #pragma unroll
    for (int i = 0; i < 2; ++i)
        #pragma unroll
        for (int j = 0; j < 2; ++j) acc[i][j] = (f32x16)0.0f;

    float bestd[2][16];
    int   besti[2][16];
    #pragma unroll
    for (int i = 0; i < 2; ++i)
        #pragma unroll
        for (int r = 0; r < 16; ++r) { bestd[i][r] = 3.4e38f; besti[i][r] = 0; }

    // B fragment loads: byte = csp*131072 + wv*32768 + j*16384 + kc*2048
    //                        + kk*1024 + lane*16
    // uniform part -> SGPR base; lane*16 -> voffset; j/kk -> immediates.
    const char* ehW = (const char*)e_hi + (size_t)wv * 32768;
    const char* elW = (const char*)e_lo + (size_t)wv * 32768;
    uint4 b0h[4], b0l[4], b1h[4], b1l[4];
    auto loadB = [&](int s, uint4* bh, uint4* bl) {
        const int off = ((s >> 3) << 17) + ((s & 7) << 11);   // uniform (SALU)
        const char* ph = ehW + off;
        const char* pl = elW + off;
        bh[0] = *(const uint4*)(ph + vOff);            // j=0,kk=0
        bh[1] = *(const uint4*)(ph + vOff + 1024);     // j=0,kk=1
        bh[2] = *(const uint4*)(ph + vOff + 16384);    // j=1,kk=0
        bh[3] = *(const uint4*)(ph + vOff + 17408);    // j=1,kk=1
        bl[0] = *(const uint4*)(pl + vOff);
        bl[1] = *(const uint4*)(pl + vOff + 1024);
        bl[2] = *(const uint4*)(pl + vOff + 16384);
        bl[3] = *(const uint4*)(pl + vOff + 17408);
    };
    // A LDS reads: byte = i*16384 + kc*2048 + kk*1024 + lane*16
    auto compute = [&](int s, const uint4* bh4, const uint4* bl4) {
        const int kcoff = (s & 7) << 11;               // uniform (SALU)
        const char* pa = (const char*)Ah + vOff + kcoff;
        const char* pb = (const char*)Al + vOff + kcoff;
        #pragma unroll
        for (int kk = 0; kk < 2; ++kk) {
            bf16x8 bh[2], bl[2], ah[2], al[2];
            #pragma unroll
            for (int j = 0; j < 2; ++j) {
                bh[j] = __builtin_bit_cast(bf16x8, bh4[j * 2 + kk]);
                bl[j] = __builtin_bit_cast(bf16x8, bl4[j * 2 + kk]);
            }
            #pragma unroll
            for (int i = 0; i < 2; ++i) {
                ah[i] = __builtin_bit_cast(bf16x8,
                    *(const uint4*)(pa + i * 16384 + kk * 1024));
                al[i] = __builtin_bit_cast(bf16x8,
                    *(const uint4*)(pb + i * 16384 + kk * 1024));
            }
            // combos OUTERMOST: same-acc MFMAs are 4 apart (no dep bubbles)
            #pragma unroll
            for (int j = 0; j < 2; ++j)
                #pragma unroll
                for (int i = 0; i < 2; ++i)
                    acc[i][j] = __builtin_amdgcn_mfma_f32_32x32x16_bf16(ah[i], bh[j], acc[i][j], 0, 0, 0);
            #pragma unroll
            for (int j = 0; j < 2; ++j)
                #pragma unroll
                for (int i = 0; i < 2; ++i)
                    acc[i][j] = __builtin_amdgcn_mfma_f32_32x32x16_bf16(al[i], bh[j], acc[i][j], 0, 0, 0);
            #pragma unroll
            for (int j = 0; j < 2; ++j)
                #pragma unroll
                for (int i = 0; i < 2; ++i)
                    acc[i][j] = __builtin_amdgcn_mfma_f32_32x32x16_bf16(ah[i], bl[j], acc[i][j], 0, 0, 0);
        }
        if ((s & 7) == 7) {   // end of this 256-code split: fold distances
            const int csp = s >> 3;
            #pragma unroll
            for (int j = 0; j < 2; ++j) {
                const int col = csp * 256 + wv * 64 + j * 32 + l31;
                const float en = enorm[col];
                #pragma unroll
                for (int i = 0; i < 2; ++i)
                    #pragma unroll
                    for (int r = 0; r < 16; ++r) {
                        const float d = fmaf(-2.0f, acc[i][j][r], en);
                        // strict <: fold candidates ascend in col (R12 proven)
                        if (d < bestd[i][r]) { bestd[i][r] = d; besti[i][r] = col; }
                    }
            }
            #pragma unroll
            for (int i = 0; i < 2; ++i)
                #pragma unroll
                for (int j = 0; j < 2; ++j) acc[i][j] = (f32x16)0.0f;
        }
    };

    loadB(0, b0h, b0l);
    for (int s = 0; s < 32; s += 2) {
        loadB(s + 1, b1h, b1l);
        compute(s, b0h, b0l);
        if (s + 2 < 32) loadB(s + 2, b0h, b0l);
        compute(s + 1, b1h, b1l);
    }

    // ---- butterfly over the 32 col lanes (keeps lane>>5 fixed) ----
    #pragma unroll
    for (int m = 1; m < 32; m <<= 1) {
        #pragma unroll
        for (int i = 0; i < 2; ++i)
            #pragma unroll
            for (int r = 0; r < 16; ++r) {
                const float od = __shfl_xor(bestd[i][r], m);
                const int   oi = __shfl_xor(besti[i][r], m);
                if (od < bestd[i][r] || (od == bestd[i][r] && oi < besti[i][r])) {
                    bestd[i][r] = od; besti[i][r] = oi;
                }
            }
    }

    // ---- merge the 4 waves via LDS -> FINAL argmin; write idx/counts ----
    __syncthreads();
    float* mg_d = (float*)Ah;                 // [4][64] floats
    int*   mg_i = (int*)Ah + 256;             // [4][64] ints
    if (l31 == 0) {
        #pragma unroll
        for (int i = 0; i < 2; ++i)
            #pragma unroll
            for (int r = 0; r < 16; ++r) {
                const int rloc = i * 32 + (r & 3) + 8 * (r >> 2) + 4 * lh;
                mg_d[wv * 64 + rloc] = bestd[i][r];
                mg_i[wv * 64 + rloc] = besti[i][r];
            }
    }
    __syncthreads();
    if (tid < 64) {
        float d0 = mg_d[tid];
        int   i0 = mg_i[tid];
        #pragma unroll
        for (int w = 1; w < 4; ++w) {   // wave col-ranges interleave: full comparator
            const float dw = mg_d[w * 64 + tid];
            const int   iw = mg_i[w * 64 + tid];
            if (dw < d0 || (dw == d0 && iw < i0)) { d0 = dw; i0 = iw; }
        }
        const int n = row0 + tid;
        idx[n] = i0; idxf[n] = (float)i0;
        atomicAdd(&cnt[i0], 1);
        mg_i[tid] = i0;                  // publish final codes for the gather
    }
    __syncthreads();

    // ---- gather z_q: each wave writes 16 rows (emb is L2/L3-resident) ----
    #pragma unroll 4
    for (int r = 0; r < 16; ++r) {
        const int row = wv * 16 + r;
        const int code = mg_i[row];
        const float4 e4 = *(const float4*)(emb + (size_t)code * 256 + lane * 4);
        *(float4*)(out_zq + (size_t)(row0 + row) * 256 + lane * 4) = e4;
    }
}

// ============ kernel 2: scatter (self-computed prefix) ============
// Each of the 128 blocks redundantly computes the exclusive prefix of cnt
// (1024 ints, L2-hot) into LDS sbase, then scatters its 256 rows:
// within-code rank via cursor atomics (cursor zeroed by esplit),
// final slot = sbase[k] + rank. No cross-block communication.
__global__ __launch_bounds__(256)
void scatter_kernel(const int* __restrict__ idx, const int* __restrict__ cnt,
                    int* __restrict__ cursor, int* __restrict__ sorted) {
    __shared__ int sbase[1024];
    __shared__ int wsum[4];
    const int t = threadIdx.x, lane = t & 63, wv = t >> 6;

    int c[4]; int ts = 0;
    #pragma unroll
    for (int i = 0; i < 4; ++i) { c[i] = cnt[t * 4 + i]; ts += c[i]; }
    int v = ts;
    #pragma unroll
    for (int o = 1; o < 64; o <<= 1) { const int u = __shfl_up(v, o); if (lane >= o) v += u; }
    if (lane == 63) wsum[wv] = v;
    __syncthreads();
    int wbase = 0;
    #pragma unroll
    for (int w = 0; w < 4; ++w) if (w < wv) wbase += wsum[w];
    int base = wbase + v - ts;                // exclusive prefix, codes ascending
    #pragma unroll
    for (int i = 0; i < 4; ++i) { sbase[t * 4 + i] = base; base += c[i]; }
    __syncthreads();

    const int n = blockIdx.x * 256 + t;
    const int k = idx[n];
    const int r = atomicAdd(&cursor[k], 1);
    sorted[sbase[k] + r] = n;
}

// ============ kernel 3: dw + loss — wave per 16 sorted rows (R5 PROVEN) ============
// 16 rows/wave is the measured optimum (64/16/8 tried; 8 doubled flush
// atomics and lost 15 us). loss per run computed algebraically:
// sum||z-e||^2 = sum(z^2) - 2 e.S + cnt*||e||^2
__global__ __launch_bounds__(256)
void dw_kernel(const float* __restrict__ z, const float* __restrict__ emb,
               const float* __restrict__ enorm,
               const int* __restrict__ sorted, const int* __restrict__ idx,
               float* __restrict__ dwacc, float* __restrict__ lossbuf) {
    const int lane = threadIdx.x & 63;
    const int w    = blockIdx.x * 4 + (threadIdx.x >> 6);
    const int r0   = w * 16;
    const int srow = sorted[r0 + (lane & 15)];
    const int skey = idx[srow];

    float4 s = make_float4(0.f, 0.f, 0.f, 0.f);
    float sumsq = 0.f;
    int cntr = 0;
    int krun = __shfl(skey, 0);

    auto flush = [&](int k) {
        const float4 e = *(const float4*)(emb + (size_t)k * 256 + lane * 4);
        float val = sumsq - 2.0f * (e.x * s.x + e.y * s.y + e.z * s.z + e.w * s.w);
        #pragma unroll
        for (int off = 32; off > 0; off >>= 1) val += __shfl_down(val, off);
        if (lane == 0) atomicAdd(&lossbuf[k & 255], val + (float)cntr * enorm[k]);
        float* p = dwacc + (size_t)k * 256 + lane * 4;
        atomicAdd(p + 0, s.x); atomicAdd(p + 1, s.y);
        atomicAdd(p + 2, s.z); atomicAdd(p + 3, s.w);
    };

    #pragma unroll 8
    for (int j = 0; j < 16; ++j) {
        const int row = __shfl(srow, j);
        const int k   = __shfl(skey, j);
        if (k != krun) {
            flush(krun);
            s = make_float4(0.f, 0.f, 0.f, 0.f);
            sumsq = 0.f; cntr = 0; krun = k;
        }
        const float4 v = *(const float4*)(z + (size_t)row * 256 + lane * 4);
        s.x += v.x; s.y += v.y; s.z += v.z; s.w += v.w;
        sumsq += v.x * v.x + v.y * v.y + v.z * v.z + v.w * v.w;
        ++cntr;
    }
    flush(krun);
}

// ============ kernel 4: EMA-w / embedding epilogue (self-computed n_total) ============
__global__ __launch_bounds__(256)
void update_w_kernel(const float* __restrict__ ema_cs, const int* __restrict__ cnt,
                     const float* __restrict__ ema_w, const float* __restrict__ dwacc,
                     const float* __restrict__ lossbuf,
                     float* __restrict__ out_cs,
                     float* __restrict__ out_emb, float* __restrict__ out_emaw,
                     float* __restrict__ out_loss) {
    __shared__ float red[256];
    const int t = threadIdx.x;

    // redundant n_total reduction (matches scan's f-sum semantics)
    float fv[4]; float fsum = 0.f;
    #pragma unroll
    for (int i = 0; i < 4; ++i) {
        const int k4 = t * 4 + i;
        const float f = DECAY_F * ema_cs[k4] + OMD_F * (float)cnt[k4];
        fv[i] = f; fsum += f;
    }
    red[t] = fsum; __syncthreads();
    #pragma unroll
    for (int off = 128; off > 0; off >>= 1) {
        if (t < off) red[t] += red[t + off];
        __syncthreads();
    }
    const float n_total = red[0];
    __syncthreads();                 // red reused below by block 0

    if (blockIdx.x == 0) {
        #pragma unroll
        for (int i = 0; i < 4; ++i) out_cs[t * 4 + i] = fv[i];
        red[t] = lossbuf[t]; __syncthreads();
        #pragma unroll
        for (int off = 128; off > 0; off >>= 1) {
            if (t < off) red[t] += red[t + off];
            __syncthreads();
        }
        if (t == 0) out_loss[0] = 1.25f * red[0] / 8388608.0f;
    }

    const int g = blockIdx.x * 256 + t;          // float4 slot, 0..65535
    const int k = g >> 6;
    const float fk = DECAY_F * ema_cs[k] + OMD_F * (float)cnt[k];
    const float cs = (fk + EPS_F) / (n_total + 1024.0f * EPS_F) * n_total;

    const float4 w4 = *(const float4*)(ema_w + (size_t)g * 4);
    const float4 d4 = *(const float4*)(dwacc + (size_t)g * 4);
    float4 nw, ne;
    nw.x = DECAY_F * w4.x + OMD_F * d4.x;
    nw.y = DECAY_F * w4.y + OMD_F * d4.y;
    nw.z = DECAY_F * w4.z + OMD_F * d4.z;
    nw.w = DECAY_F * w4.w + OMD_F * d4.w;
    ne.x = nw.x / cs; ne.y = nw.y / cs; ne.z = nw.z / cs; ne.w = nw.w / cs;
    *(float4*)(out_emaw + (size_t)g * 4) = nw;
    *(float4*)(out_emb  + (size_t)g * 4) = ne;
}

// ======================= launcher =======================
extern "C" void kernel_launch(void* const* d_in, const int* in_sizes, int n_in,
                              void* d_out, int out_size, void* d_ws, size_t ws_size,
                              hipStream_t stream) {
    const float* z      = (const float*)d_in[0];
    const float* emb    = (const float*)d_in[1];
    const float* ema_cs = (const float*)d_in[2];
    const float* ema_w  = (const float*)d_in[3];

    float* out = (float*)d_out;
    char*  wsb = (char*)d_ws;

    int*            cnt     = (int*)(wsb + WSB_CNTI);
    float*          lossbuf = (float*)(wsb + WSB_LOSS);
    float*          dwacc   = (float*)(wsb + WSB_DWACC);
    float*          enorm   = (float*)(wsb + WSB_ENORM);
    int*            idx     = (int*)(wsb + WSB_IDX);
    unsigned short* e_hi    = (unsigned short*)(wsb + WSB_EHI);
    unsigned short* e_lo    = (unsigned short*)(wsb + WSB_ELO);
    int*            sorted  = (int*)(wsb + WSB_SORT);
    int*            cursor  = (int*)(wsb + WSB_CURS);

    float* out_zq   = out + OUT_ZQ;
    float* out_loss = out + OUT_LOSS;
    float* out_idxf = out + OUT_IDX;
    float* out_emb  = out + OUT_EMB;
    float* out_cs   = out + OUT_CS;
    float* out_emaw = out + OUT_EMAW;

    esplit_enorm_kernel<<<256, 256, 0, stream>>>(emb, e_hi, e_lo, enorm,
                                                 dwacc, cnt, lossbuf, cursor);
    argmin_kernel<<<512, 256, 0, stream>>>(z, e_hi, e_lo, enorm, emb,
                                           idx, out_idxf, out_zq, cnt);
    scatter_kernel<<<128, 256, 0, stream>>>(idx, cnt, cursor, sorted);
    dw_kernel<<<512, 256, 0, stream>>>(z, emb, enorm, sorted, idx, dwacc, lossbuf);
    update_w_kernel<<<256, 256, 0, stream>>>(ema_cs, cnt, ema_w, dwacc, lossbuf,
                                             out_cs, out_emb, out_emaw, out_loss);
}